// Round 1
// baseline (1328.300 us; speedup 1.0000x reference)
//
#include <hip/hip_runtime.h>
#include <hip/hip_bf16.h>
#include <math.h>

// Problem: B=2,H=16,SQ=SK=2048,D=M=128
#define NBH   32
#define SEQ   2048
#define DD    128
#define MM    128
#define NROWS (NBH*SEQ)          // 65536 rows each for q and k

typedef unsigned short u16;
typedef unsigned int   u32;
typedef float  f32x4  __attribute__((ext_vector_type(4)));
typedef __bf16 bf16x8 __attribute__((ext_vector_type(8)));

#define SCALE_F 0.009791516697777346f  // sqrt(pi/2)/128
#define TAU 0.3f

// ---------- helpers ----------
static __device__ __forceinline__ u16 f2bf(float f) {
  union { float f; u32 u; } v; v.f = f;
  u32 u = v.u;
  u += 0x7fffu + ((u >> 16) & 1u);   // RNE
  return (u16)(u >> 16);
}

// MFMA on a 128x128 (rows) x 128x128 (cols) pair of bf16 LDS tiles.
// LDS layout: [row][chunk16B], chunk stored at (c ^ (row&7)).
// Wave w: wr=w>>1, wc=w&1 owns 64x64 output; acc[4][4] of f32x4.
static __device__ __forceinline__ void mfma_tile(const u16* lA, const u16* lB,
                                                 int wave, int lane,
                                                 f32x4 acc[4][4]) {
  const int wr = wave >> 1, wc = wave & 1;
  const int lrow = lane & 15, lkg = lane >> 4;
#pragma unroll
  for (int kk = 0; kk < 4; ++kk) {
    bf16x8 af[4], bfr[4];
    const int c = kk * 4 + lkg;
#pragma unroll
    for (int a = 0; a < 4; ++a) {
      const int r  = wr * 64 + a * 16 + lrow;
      const int r2 = wc * 64 + a * 16 + lrow;
      af[a]  = *(const bf16x8*)((const char*)lA + r  * 256 + ((c ^ (r  & 7)) << 4));
      bfr[a] = *(const bf16x8*)((const char*)lB + r2 * 256 + ((c ^ (r2 & 7)) << 4));
    }
#pragma unroll
    for (int a = 0; a < 4; ++a)
#pragma unroll
      for (int b = 0; b < 4; ++b)
        acc[a][b] = __builtin_amdgcn_mfma_f32_16x16x32_bf16(af[a], bfr[b], acc[a][b], 0, 0, 0);
  }
}

// ---------- kernel C: S (f32, [m][d]) -> bf16 linear ----------
__global__ __launch_bounds__(256) void k_convS(const float* __restrict__ S,
                                               u16* __restrict__ Sb) {
  int i = blockIdx.x * 256 + threadIdx.x;  // grid 64 -> 16384
  Sb[i] = f2bf(S[i]);
}

// ---------- kernel N: sn[row] = scale * ||k_row|| ----------
__global__ __launch_bounds__(256) void k_norm(const float* __restrict__ K,
                                              float* __restrict__ sn) {
  int t = threadIdx.x;
  int row = blockIdx.x * 64 + (t >> 2);
  int q4 = t & 3;
  const f32x4* base = (const f32x4*)(K + (size_t)row * DD);
  float s = 0.f;
#pragma unroll
  for (int j = 0; j < 8; ++j) {
    f32x4 v = base[q4 + j * 4];
    s += v.x * v.x + v.y * v.y + v.z * v.z + v.w * v.w;
  }
  s += __shfl_xor(s, 1);
  s += __shfl_xor(s, 2);
  if (q4 == 0) sn[row] = SCALE_F * sqrtf(s);
}

// ---------- kernel P: projection rows(128-tile) @ S^T via MFMA ----------
__global__ __launch_bounds__(256) void k_proj(
    const float* __restrict__ Q, const float* __restrict__ K,
    const u16* __restrict__ Sb, u16* __restrict__ Sqb, u16* __restrict__ Sgn,
    u32* __restrict__ wl, u32* __restrict__ wlcnt, u32 wlcap) {
  __shared__ __align__(16) u16 lA[128 * 128];
  __shared__ __align__(16) u16 lB[128 * 128];
  const int tid = threadIdx.x;
  const int tile = blockIdx.x;           // 0..511 q, 512..1023 k
  const bool isK = (tile >= 512);
  const int row0 = (isK ? (tile - 512) : tile) * 128;
  const float* src = isK ? K : Q;

  // stage S_bf16 (32KB linear global -> swizzled LDS)
  {
    const f32x4* g = (const f32x4*)Sb;
#pragma unroll
    for (int j = 0; j < 8; ++j) {
      int i = tid + j * 256;             // 16B-chunk index
      int r = i >> 4, c = i & 15;
      f32x4 v = g[i];
      *(f32x4*)((char*)lB + r * 256 + ((c ^ (r & 7)) << 4)) = v;
    }
  }
  // stage A rows: f32 global -> bf16 swizzled LDS
  {
    const float* abase = src + (size_t)row0 * DD;
#pragma unroll
    for (int j = 0; j < 8; ++j) {
      int i = tid + j * 256;             // bf16 16B-chunk index
      int r = i >> 4, c = i & 15;
      const f32x4* gp = (const f32x4*)(abase + (size_t)r * DD + c * 8);
      f32x4 v0 = gp[0], v1 = gp[1];
      union { u16 h[8]; f32x4 v; } pk;
      pk.h[0] = f2bf(v0.x); pk.h[1] = f2bf(v0.y); pk.h[2] = f2bf(v0.z); pk.h[3] = f2bf(v0.w);
      pk.h[4] = f2bf(v1.x); pk.h[5] = f2bf(v1.y); pk.h[6] = f2bf(v1.z); pk.h[7] = f2bf(v1.w);
      *(f32x4*)((char*)lA + r * 256 + ((c ^ (r & 7)) << 4)) = pk.v;
    }
  }
  __syncthreads();

  const int wave = tid >> 6, lane = tid & 63;
  f32x4 acc[4][4];
#pragma unroll
  for (int a = 0; a < 4; ++a)
#pragma unroll
    for (int b = 0; b < 4; ++b) acc[a][b] = (f32x4){0.f, 0.f, 0.f, 0.f};

  mfma_tile(lA, lB, wave, lane, acc);

  const int wr = wave >> 1, wc = wave & 1;
#pragma unroll
  for (int a = 0; a < 4; ++a) {
#pragma unroll
    for (int b = 0; b < 4; ++b) {
      const int rloc = wr * 64 + a * 16 + (lane >> 4) * 4;
      const int m = wc * 64 + b * 16 + (lane & 15);
#pragma unroll
      for (int j = 0; j < 4; ++j) {
        const float v = acc[a][b][j];
        const int row = row0 + rloc + j;
        if (!isK) {
          Sqb[(size_t)row * MM + m] = f2bf(v);
        } else {
          Sgn[(size_t)row * MM + m] = (v >= 0.f) ? 0x3F80 : 0xBF80;
          if (fabsf(v) < TAU && wlcap) {
            u32 idx = atomicAdd(wlcnt, 1u);
            if (idx < wlcap) wl[idx] = ((u32)row << 7) | (u32)m;
          }
        }
      }
    }
  }
}

// ---------- kernel R: f64 recompute of borderline signs ----------
__global__ __launch_bounds__(256) void k_fix(
    const float* __restrict__ K, const float* __restrict__ S,
    const u32* __restrict__ wl, const u32* __restrict__ wlcnt,
    u16* __restrict__ Sgn, u32 wlcap) {
  u32 n = *wlcnt; if (n > wlcap) n = wlcap;
  u32 g = blockIdx.x * 256 + threadIdx.x;
  for (u32 e = g; e < n; e += 256u * 1024u) {
    u32 code = wl[e];
    u32 row = code >> 7, m = code & 127u;
    const float* kr = K + (size_t)row * DD;
    const float* sr = S + (size_t)m * DD;
    double acc = 0.0;
#pragma unroll 4
    for (int d = 0; d < DD; ++d) acc += (double)kr[d] * (double)sr[d];
    Sgn[(size_t)row * MM + m] = (acc >= 0.0) ? 0x3F80 : 0xBF80;
  }
}

// ---------- kernel G: out = (Sq @ sign^T) * sn[col], per head ----------
__global__ __launch_bounds__(256) void k_gemm(
    const u16* __restrict__ Sqb, const u16* __restrict__ Sgn,
    const float* __restrict__ sn, float* __restrict__ out) {
  __shared__ __align__(16) u16 lA[128 * 128];
  __shared__ __align__(16) u16 lB[128 * 128];
  const int tid = threadIdx.x;
  const int tn = blockIdx.x, tm = blockIdx.y, bh = blockIdx.z;
  const u16* Abase = Sqb + ((size_t)bh * SEQ + tm * 128) * MM;
  const u16* Bbase = Sgn + ((size_t)bh * SEQ + tn * 128) * MM;
#pragma unroll
  for (int j = 0; j < 8; ++j) {
    int i = tid + j * 256;
    int r = i >> 4, c = i & 15;
    f32x4 va = *(const f32x4*)((const char*)Abase + (size_t)i * 16);
    f32x4 vb = *(const f32x4*)((const char*)Bbase + (size_t)i * 16);
    int off = r * 256 + ((c ^ (r & 7)) << 4);
    *(f32x4*)((char*)lA + off) = va;
    *(f32x4*)((char*)lB + off) = vb;
  }
  __syncthreads();

  const int wave = tid >> 6, lane = tid & 63;
  f32x4 acc[4][4];
#pragma unroll
  for (int a = 0; a < 4; ++a)
#pragma unroll
    for (int b = 0; b < 4; ++b) acc[a][b] = (f32x4){0.f, 0.f, 0.f, 0.f};

  mfma_tile(lA, lB, wave, lane, acc);

  const int wr = wave >> 1, wc = wave & 1;
  const size_t outbase = (size_t)bh * SEQ * SEQ;
#pragma unroll
  for (int b = 0; b < 4; ++b) {
    const int kcol = tn * 128 + wc * 64 + b * 16 + (lane & 15);
    const float s = sn[bh * SEQ + kcol];
#pragma unroll
    for (int a = 0; a < 4; ++a) {
      const int qrow0 = tm * 128 + wr * 64 + a * 16 + (lane >> 4) * 4;
#pragma unroll
      for (int j = 0; j < 4; ++j) {
        out[outbase + (size_t)(qrow0 + j) * SEQ + kcol] = acc[a][b][j] * s;
      }
    }
  }
}

// ---------- launch ----------
extern "C" void kernel_launch(void* const* d_in, const int* in_sizes, int n_in,
                              void* d_out, int out_size, void* d_ws, size_t ws_size,
                              hipStream_t stream) {
  const float* q = (const float*)d_in[0];
  const float* k = (const float*)d_in[1];
  const float* S = (const float*)d_in[2];
  float* out = (float*)d_out;
  char* ws = (char*)d_ws;

  // workspace layout (bytes)
  const size_t off_Sq  = 0;                     // 65536*128*2 = 16 MiB
  const size_t off_Sg  = 16777216;              // 16 MiB
  const size_t off_sn  = 33554432;              // 256 KiB
  const size_t off_Sb  = 33816576;              // 32 KiB
  const size_t off_cnt = 33849344;              // 256 B
  const size_t off_wl  = 33849600;              // worklist

  u16*   Sqb = (u16*)(ws + off_Sq);
  u16*   Sgn = (u16*)(ws + off_Sg);
  float* sn  = (float*)(ws + off_sn);
  u16*   Sb  = (u16*)(ws + off_Sb);
  u32*   cnt = (u32*)(ws + off_cnt);
  u32*   wl  = (u32*)(ws + off_wl);

  u32 wlcap = 0;
  if (ws_size > off_wl + 16) {
    size_t rem = (ws_size - off_wl) / 4;
    wlcap = (u32)(rem > 2097152 ? 2097152 : rem);
  }

  hipMemsetAsync(cnt, 0, 4, stream);
  k_convS<<<64, 256, 0, stream>>>(S, Sb);
  k_norm<<<1024, 256, 0, stream>>>(k, sn);
  k_proj<<<1024, 256, 0, stream>>>(q, k, Sb, Sqb, Sgn, wl, cnt, wlcap);
  k_fix<<<1024, 256, 0, stream>>>(k, S, wl, cnt, Sgn, wlcap);
  dim3 g(16, 16, NBH);
  k_gemm<<<g, 256, 0, stream>>>(Sqb, Sgn, sn, out);
}

// Round 2
// 220.491 us; speedup vs baseline: 6.0243x; 6.0243x over previous
//
#include <hip/hip_runtime.h>
#include <hip/hip_bf16.h>
#include <math.h>

// Problem: B=2,H=16,SQ=SK=2048,D=M=128
#define NBH   32
#define SEQ   2048
#define DD    128
#define MM    128

typedef unsigned short u16;
typedef unsigned int   u32;
typedef float  f32x4  __attribute__((ext_vector_type(4)));
typedef __bf16 bf16x8 __attribute__((ext_vector_type(8)));

#define SCALE_F 0.009791516697777346f  // sqrt(pi/2)/128
#define TAU 0.3f
#define LCAP 4096                      // per-block candidate cap (expected ~344)

// ---------- helpers ----------
static __device__ __forceinline__ u16 f2bf(float f) {
  union { float f; u32 u; } v; v.f = f;
  u32 u = v.u;
  u += 0x7fffu + ((u >> 16) & 1u);   // RNE
  return (u16)(u >> 16);
}

// MFMA on a 128x128 (rows) x 128x128 (cols) pair of bf16 LDS tiles.
// LDS layout: [row][chunk16B], chunk stored at (c ^ (row&7)).
// Wave w: wr=w>>1, wc=w&1 owns 64x64 output; acc[4][4] of f32x4.
static __device__ __forceinline__ void mfma_tile(const u16* lA, const u16* lB,
                                                 int wave, int lane,
                                                 f32x4 acc[4][4]) {
  const int wr = wave >> 1, wc = wave & 1;
  const int lrow = lane & 15, lkg = lane >> 4;
#pragma unroll
  for (int kk = 0; kk < 4; ++kk) {
    bf16x8 af[4], bfr[4];
    const int c = kk * 4 + lkg;
#pragma unroll
    for (int a = 0; a < 4; ++a) {
      const int r  = wr * 64 + a * 16 + lrow;
      const int r2 = wc * 64 + a * 16 + lrow;
      af[a]  = *(const bf16x8*)((const char*)lA + r  * 256 + ((c ^ (r  & 7)) << 4));
      bfr[a] = *(const bf16x8*)((const char*)lB + r2 * 256 + ((c ^ (r2 & 7)) << 4));
    }
#pragma unroll
    for (int a = 0; a < 4; ++a)
#pragma unroll
      for (int b = 0; b < 4; ++b)
        acc[a][b] = __builtin_amdgcn_mfma_f32_16x16x32_bf16(af[a], bfr[b], acc[a][b], 0, 0, 0);
  }
}

// ---------- kernel C: S (f32, [m][d]) -> bf16 linear ----------
__global__ __launch_bounds__(256) void k_convS(const float* __restrict__ S,
                                               u16* __restrict__ Sb) {
  int i = blockIdx.x * 256 + threadIdx.x;  // grid 64 -> 16384
  Sb[i] = f2bf(S[i]);
}

// ---------- kernel N: sn[row] = scale * ||k_row|| ----------
__global__ __launch_bounds__(256) void k_norm(const float* __restrict__ K,
                                              float* __restrict__ sn) {
  int t = threadIdx.x;
  int row = blockIdx.x * 64 + (t >> 2);
  int q4 = t & 3;
  const f32x4* base = (const f32x4*)(K + (size_t)row * DD);
  float s = 0.f;
#pragma unroll
  for (int j = 0; j < 8; ++j) {
    f32x4 v = base[q4 + j * 4];
    s += v.x * v.x + v.y * v.y + v.z * v.z + v.w * v.w;
  }
  s += __shfl_xor(s, 1);
  s += __shfl_xor(s, 2);
  if (q4 == 0) sn[row] = SCALE_F * sqrtf(s);
}

// ---------- kernel P: projection rows(128-tile) @ S^T via MFMA ----------
__global__ __launch_bounds__(256) void k_proj(
    const float* __restrict__ Q, const float* __restrict__ K,
    const u16* __restrict__ Sb, u16* __restrict__ Sqb, u16* __restrict__ Sgn,
    u32* __restrict__ wl, u32* __restrict__ wlcnt, u32 wlcap) {
  __shared__ __align__(16) u16 lA[128 * 128];   // reused as candidate buffer post-MFMA
  __shared__ __align__(16) u16 lB[128 * 128];
  __shared__ u32 lcnt, lbase;
  const int tid = threadIdx.x;
  const int tile = blockIdx.x;           // 0..511 q, 512..1023 k
  const bool isK = (tile >= 512);
  const int row0 = (isK ? (tile - 512) : tile) * 128;
  const float* src = isK ? K : Q;

  if (tid == 0) lcnt = 0;

  // stage S_bf16 (32KB linear global -> swizzled LDS)
  {
    const f32x4* g = (const f32x4*)Sb;
#pragma unroll
    for (int j = 0; j < 8; ++j) {
      int i = tid + j * 256;             // 16B-chunk index
      int r = i >> 4, c = i & 15;
      f32x4 v = g[i];
      *(f32x4*)((char*)lB + r * 256 + ((c ^ (r & 7)) << 4)) = v;
    }
  }
  // stage A rows: f32 global -> bf16 swizzled LDS
  {
    const float* abase = src + (size_t)row0 * DD;
#pragma unroll
    for (int j = 0; j < 8; ++j) {
      int i = tid + j * 256;             // bf16 16B-chunk index
      int r = i >> 4, c = i & 15;
      const f32x4* gp = (const f32x4*)(abase + (size_t)r * DD + c * 8);
      f32x4 v0 = gp[0], v1 = gp[1];
      union { u16 h[8]; f32x4 v; } pk;
      pk.h[0] = f2bf(v0.x); pk.h[1] = f2bf(v0.y); pk.h[2] = f2bf(v0.z); pk.h[3] = f2bf(v0.w);
      pk.h[4] = f2bf(v1.x); pk.h[5] = f2bf(v1.y); pk.h[6] = f2bf(v1.z); pk.h[7] = f2bf(v1.w);
      *(f32x4*)((char*)lA + r * 256 + ((c ^ (r & 7)) << 4)) = pk.v;
    }
  }
  __syncthreads();

  const int wave = tid >> 6, lane = tid & 63;
  f32x4 acc[4][4];
#pragma unroll
  for (int a = 0; a < 4; ++a)
#pragma unroll
    for (int b = 0; b < 4; ++b) acc[a][b] = (f32x4){0.f, 0.f, 0.f, 0.f};

  mfma_tile(lA, lB, wave, lane, acc);

  // all waves done reading lA before it is reused as the candidate buffer
  __syncthreads();
  u32* lbuf = (u32*)lA;

  const int wr = wave >> 1, wc = wave & 1;
#pragma unroll
  for (int a = 0; a < 4; ++a) {
#pragma unroll
    for (int b = 0; b < 4; ++b) {
      const int rloc = wr * 64 + a * 16 + (lane >> 4) * 4;
      const int m = wc * 64 + b * 16 + (lane & 15);
#pragma unroll
      for (int j = 0; j < 4; ++j) {
        const float v = acc[a][b][j];
        const int row = row0 + rloc + j;
        if (!isK) {
          Sqb[(size_t)row * MM + m] = f2bf(v);
        } else {
          Sgn[(size_t)row * MM + m] = (v >= 0.f) ? 0x3F80 : 0xBF80;
          if (fabsf(v) < TAU && wlcap) {
            u32 p = atomicAdd(&lcnt, 1u);          // LDS atomic (cheap)
            u32 code = ((u32)row << 7) | (u32)m;
            if (p < LCAP) lbuf[p] = code;
            else {                                  // ~never: direct fallback
              u32 idx = atomicAdd(wlcnt, 1u);
              if (idx < wlcap) wl[idx] = code;
            }
          }
        }
      }
    }
  }

  if (isK && wlcap) {
    __syncthreads();
    if (tid == 0) {
      u32 n = lcnt; if (n > LCAP) n = LCAP;
      lbase = n ? atomicAdd(wlcnt, n) : 0u;         // ONE global atomic per block
    }
    __syncthreads();
    u32 n = lcnt; if (n > LCAP) n = LCAP;
    for (u32 i = tid; i < n; i += 256) {
      u32 dst = lbase + i;
      if (dst < wlcap) wl[dst] = lbuf[i];
    }
  }
}

// ---------- kernel R: f64 recompute of borderline signs ----------
__global__ __launch_bounds__(256) void k_fix(
    const float* __restrict__ K, const float* __restrict__ S,
    const u32* __restrict__ wl, const u32* __restrict__ wlcnt,
    u16* __restrict__ Sgn, u32 wlcap) {
  u32 n = *wlcnt; if (n > wlcap) n = wlcap;
  u32 g = blockIdx.x * 256 + threadIdx.x;
  for (u32 e = g; e < n; e += 256u * 1024u) {
    u32 code = wl[e];
    u32 row = code >> 7, m = code & 127u;
    const float* kr = K + (size_t)row * DD;
    const float* sr = S + (size_t)m * DD;
    double acc = 0.0;
#pragma unroll 4
    for (int d = 0; d < DD; ++d) acc += (double)kr[d] * (double)sr[d];
    Sgn[(size_t)row * MM + m] = (acc >= 0.0) ? 0x3F80 : 0xBF80;
  }
}

// ---------- kernel G: out = (Sq @ sign^T) * sn[col], per head ----------
__global__ __launch_bounds__(256) void k_gemm(
    const u16* __restrict__ Sqb, const u16* __restrict__ Sgn,
    const float* __restrict__ sn, float* __restrict__ out) {
  __shared__ __align__(16) u16 lA[128 * 128];
  __shared__ __align__(16) u16 lB[128 * 128];
  const int tid = threadIdx.x;
  const int tn = blockIdx.x, tm = blockIdx.y, bh = blockIdx.z;
  const u16* Abase = Sqb + ((size_t)bh * SEQ + tm * 128) * MM;
  const u16* Bbase = Sgn + ((size_t)bh * SEQ + tn * 128) * MM;
#pragma unroll
  for (int j = 0; j < 8; ++j) {
    int i = tid + j * 256;
    int r = i >> 4, c = i & 15;
    f32x4 va = *(const f32x4*)((const char*)Abase + (size_t)i * 16);
    f32x4 vb = *(const f32x4*)((const char*)Bbase + (size_t)i * 16);
    int off = r * 256 + ((c ^ (r & 7)) << 4);
    *(f32x4*)((char*)lA + off) = va;
    *(f32x4*)((char*)lB + off) = vb;
  }
  __syncthreads();

  const int wave = tid >> 6, lane = tid & 63;
  f32x4 acc[4][4];
#pragma unroll
  for (int a = 0; a < 4; ++a)
#pragma unroll
    for (int b = 0; b < 4; ++b) acc[a][b] = (f32x4){0.f, 0.f, 0.f, 0.f};

  mfma_tile(lA, lB, wave, lane, acc);

  const int wr = wave >> 1, wc = wave & 1;
  const size_t outbase = (size_t)bh * SEQ * SEQ;
#pragma unroll
  for (int b = 0; b < 4; ++b) {
    const int kcol = tn * 128 + wc * 64 + b * 16 + (lane & 15);
    const float s = sn[bh * SEQ + kcol];
#pragma unroll
    for (int a = 0; a < 4; ++a) {
      const int qrow0 = tm * 128 + wr * 64 + a * 16 + (lane >> 4) * 4;
#pragma unroll
      for (int j = 0; j < 4; ++j) {
        out[outbase + (size_t)(qrow0 + j) * SEQ + kcol] = acc[a][b][j] * s;
      }
    }
  }
}

// ---------- launch ----------
extern "C" void kernel_launch(void* const* d_in, const int* in_sizes, int n_in,
                              void* d_out, int out_size, void* d_ws, size_t ws_size,
                              hipStream_t stream) {
  const float* q = (const float*)d_in[0];
  const float* k = (const float*)d_in[1];
  const float* S = (const float*)d_in[2];
  float* out = (float*)d_out;
  char* ws = (char*)d_ws;

  // workspace layout (bytes)
  const size_t off_Sq  = 0;                     // 65536*128*2 = 16 MiB
  const size_t off_Sg  = 16777216;              // 16 MiB
  const size_t off_sn  = 33554432;              // 256 KiB
  const size_t off_Sb  = 33816576;              // 32 KiB
  const size_t off_cnt = 33849344;              // 256 B
  const size_t off_wl  = 33849600;              // worklist

  u16*   Sqb = (u16*)(ws + off_Sq);
  u16*   Sgn = (u16*)(ws + off_Sg);
  float* sn  = (float*)(ws + off_sn);
  u16*   Sb  = (u16*)(ws + off_Sb);
  u32*   cnt = (u32*)(ws + off_cnt);
  u32*   wl  = (u32*)(ws + off_wl);

  u32 wlcap = 0;
  if (ws_size > off_wl + 16) {
    size_t rem = (ws_size - off_wl) / 4;
    wlcap = (u32)(rem > 2097152 ? 2097152 : rem);
  }

  hipMemsetAsync(cnt, 0, 4, stream);
  k_convS<<<64, 256, 0, stream>>>(S, Sb);
  k_norm<<<1024, 256, 0, stream>>>(k, sn);
  k_proj<<<1024, 256, 0, stream>>>(q, k, Sb, Sqb, Sgn, wl, cnt, wlcap);
  k_fix<<<1024, 256, 0, stream>>>(k, S, wl, cnt, Sgn, wlcap);
  dim3 g(16, 16, NBH);
  k_gemm<<<g, 256, 0, stream>>>(Sqb, Sgn, sn, out);
}

// Round 3
// 171.953 us; speedup vs baseline: 7.7248x; 1.2823x over previous
//
#include <hip/hip_runtime.h>
#include <hip/hip_bf16.h>
#include <math.h>

// Problem: B=2,H=16,SQ=SK=2048,D=M=128
#define NBH   32
#define SEQ   2048
#define DD    128
#define MM    128

typedef unsigned short u16;
typedef unsigned int   u32;
typedef float  f32x4  __attribute__((ext_vector_type(4)));
typedef __bf16 bf16x8 __attribute__((ext_vector_type(8)));

#define SCALE_F 0.009791516697777346f  // sqrt(pi/2)/128
#define TAU 0.3f
#define LCAP 4096                      // per-block candidate cap (expected ~344)

// ---------- helpers ----------
static __device__ __forceinline__ u16 f2bf(float f) {
  union { float f; u32 u; } v; v.f = f;
  u32 u = v.u;
  u += 0x7fffu + ((u >> 16) & 1u);   // RNE
  return (u16)(u >> 16);
}

// MFMA on a 128x128 (rows) x 128x128 (cols) pair of bf16 LDS tiles.
// LDS layout: [row][chunk16B], chunk stored at (c ^ (row&7)).
// Wave w: wr=w>>1, wc=w&1 owns 64x64 output; acc[4][4] of f32x4.
static __device__ __forceinline__ void mfma_tile(const u16* lA, const u16* lB,
                                                 int wave, int lane,
                                                 f32x4 acc[4][4]) {
  const int wr = wave >> 1, wc = wave & 1;
  const int lrow = lane & 15, lkg = lane >> 4;
#pragma unroll
  for (int kk = 0; kk < 4; ++kk) {
    bf16x8 af[4], bfr[4];
    const int c = kk * 4 + lkg;
#pragma unroll
    for (int a = 0; a < 4; ++a) {
      const int r  = wr * 64 + a * 16 + lrow;
      const int r2 = wc * 64 + a * 16 + lrow;
      af[a]  = *(const bf16x8*)((const char*)lA + r  * 256 + ((c ^ (r  & 7)) << 4));
      bfr[a] = *(const bf16x8*)((const char*)lB + r2 * 256 + ((c ^ (r2 & 7)) << 4));
    }
#pragma unroll
    for (int a = 0; a < 4; ++a)
#pragma unroll
      for (int b = 0; b < 4; ++b)
        acc[a][b] = __builtin_amdgcn_mfma_f32_16x16x32_bf16(af[a], bfr[b], acc[a][b], 0, 0, 0);
  }
}

// stage a 128x128 f32 matrix (row-major, ld=128) into swizzled bf16 LDS
static __device__ __forceinline__ void stage_f32_to_bf16(const float* __restrict__ src,
                                                         u16* lds, int tid) {
#pragma unroll
  for (int j = 0; j < 8; ++j) {
    int i = tid + j * 256;             // bf16 16B-chunk index
    int r = i >> 4, c = i & 15;
    const f32x4* gp = (const f32x4*)(src + (size_t)r * DD + c * 8);
    f32x4 v0 = gp[0], v1 = gp[1];
    union { u16 h[8]; f32x4 v; } pk;
    pk.h[0] = f2bf(v0.x); pk.h[1] = f2bf(v0.y); pk.h[2] = f2bf(v0.z); pk.h[3] = f2bf(v0.w);
    pk.h[4] = f2bf(v1.x); pk.h[5] = f2bf(v1.y); pk.h[6] = f2bf(v1.z); pk.h[7] = f2bf(v1.w);
    *(f32x4*)((char*)lds + r * 256 + ((c ^ (r & 7)) << 4)) = pk.v;
  }
}

// ---------- kernel P: projection rows(128-tile) @ S^T via MFMA ----------
// Also: converts S f32->bf16 per block, and (for K blocks) computes
// sn[row] = SCALE * ||k_row|| from the L2-hot rows.
__global__ __launch_bounds__(256) void k_proj(
    const float* __restrict__ Q, const float* __restrict__ K,
    const float* __restrict__ S, u16* __restrict__ Sqb, u16* __restrict__ Sgn,
    float* __restrict__ sn,
    u32* __restrict__ wl, u32* __restrict__ wlcnt, u32 wlcap) {
  __shared__ __align__(16) u16 lA[128 * 128];   // reused as candidate buffer post-MFMA
  __shared__ __align__(16) u16 lB[128 * 128];
  __shared__ u32 lcnt, lbase;
  const int tid = threadIdx.x;
  const int tile = blockIdx.x;           // 0..511 q, 512..1023 k
  const bool isK = (tile >= 512);
  const int row0 = (isK ? (tile - 512) : tile) * 128;
  const float* src = isK ? K : Q;

  if (tid == 0) lcnt = 0;

  // stage S (f32 -> bf16 swizzled) and A rows
  stage_f32_to_bf16(S, lB, tid);
  stage_f32_to_bf16(src + (size_t)row0 * DD, lA, tid);

  // norms for K rows (rows are L1/L2-hot from staging): 2 threads per row
  if (isK) {
    const int row = tid >> 1, half = tid & 1;
    const f32x4* base = (const f32x4*)(src + (size_t)(row0 + row) * DD) + half * 16;
    float s = 0.f;
#pragma unroll
    for (int j = 0; j < 16; ++j) {
      f32x4 v = base[j];
      s += v.x * v.x + v.y * v.y + v.z * v.z + v.w * v.w;
    }
    s += __shfl_xor(s, 1);
    if (half == 0) sn[row0 + row] = SCALE_F * sqrtf(s);
  }
  __syncthreads();

  const int wave = tid >> 6, lane = tid & 63;
  f32x4 acc[4][4];
#pragma unroll
  for (int a = 0; a < 4; ++a)
#pragma unroll
    for (int b = 0; b < 4; ++b) acc[a][b] = (f32x4){0.f, 0.f, 0.f, 0.f};

  mfma_tile(lA, lB, wave, lane, acc);

  // all waves done reading lA before it is reused as the candidate buffer
  __syncthreads();
  u32* lbuf = (u32*)lA;

  const int wr = wave >> 1, wc = wave & 1;
#pragma unroll
  for (int a = 0; a < 4; ++a) {
#pragma unroll
    for (int b = 0; b < 4; ++b) {
      const int rloc = wr * 64 + a * 16 + (lane >> 4) * 4;
      const int m = wc * 64 + b * 16 + (lane & 15);
#pragma unroll
      for (int j = 0; j < 4; ++j) {
        const float v = acc[a][b][j];
        const int row = row0 + rloc + j;
        if (!isK) {
          Sqb[(size_t)row * MM + m] = f2bf(v);
        } else {
          Sgn[(size_t)row * MM + m] = (v >= 0.f) ? 0x3F80 : 0xBF80;
          if (fabsf(v) < TAU && wlcap) {
            u32 p = atomicAdd(&lcnt, 1u);          // LDS atomic (cheap)
            u32 code = ((u32)row << 7) | (u32)m;
            if (p < LCAP) lbuf[p] = code;
            else {                                  // ~never: direct fallback
              u32 idx = atomicAdd(wlcnt, 1u);
              if (idx < wlcap) wl[idx] = code;
            }
          }
        }
      }
    }
  }

  if (isK && wlcap) {
    __syncthreads();
    if (tid == 0) {
      u32 n = lcnt; if (n > LCAP) n = LCAP;
      lbase = n ? atomicAdd(wlcnt, n) : 0u;         // ONE global atomic per block
    }
    __syncthreads();
    u32 n = lcnt; if (n > LCAP) n = LCAP;
    for (u32 i = tid; i < n; i += 256) {
      u32 dst = lbase + i;
      if (dst < wlcap) wl[dst] = lbuf[i];
    }
  }
}

// ---------- kernel R: f64 recompute of borderline signs ----------
__global__ __launch_bounds__(256) void k_fix(
    const float* __restrict__ K, const float* __restrict__ S,
    const u32* __restrict__ wl, const u32* __restrict__ wlcnt,
    u16* __restrict__ Sgn, u32 wlcap) {
  u32 n = *wlcnt; if (n > wlcap) n = wlcap;
  u32 g = blockIdx.x * 256 + threadIdx.x;
  for (u32 e = g; e < n; e += 256u * 1024u) {
    u32 code = wl[e];
    u32 row = code >> 7, m = code & 127u;
    const float* kr = K + (size_t)row * DD;
    const float* sr = S + (size_t)m * DD;
    double acc = 0.0;
#pragma unroll 4
    for (int d = 0; d < DD; ++d) acc += (double)kr[d] * (double)sr[d];
    Sgn[(size_t)row * MM + m] = (acc >= 0.0) ? 0x3F80 : 0xBF80;
  }
}

// ---------- kernel G: out = (Sq @ sign^T) * sn[col], per head ----------
// Epilogue: acc -> swizzled f32 LDS tile -> row-major readback -> nt dwordx4.
__global__ __launch_bounds__(256) void k_gemm(
    const u16* __restrict__ Sqb, const u16* __restrict__ Sgn,
    const float* __restrict__ sn, float* __restrict__ out) {
  __shared__ __align__(16) u16 lds2[2 * 128 * 128];   // 64 KB
  u16* lA = lds2;
  u16* lB = lds2 + 128 * 128;
  const int tid = threadIdx.x;
  const int tn = blockIdx.x, tm = blockIdx.y, bh = blockIdx.z;
  const u16* Abase = Sqb + ((size_t)bh * SEQ + tm * 128) * MM;
  const u16* Bbase = Sgn + ((size_t)bh * SEQ + tn * 128) * MM;
#pragma unroll
  for (int j = 0; j < 8; ++j) {
    int i = tid + j * 256;
    int r = i >> 4, c = i & 15;
    f32x4 va = *(const f32x4*)((const char*)Abase + (size_t)i * 16);
    f32x4 vb = *(const f32x4*)((const char*)Bbase + (size_t)i * 16);
    int off = r * 256 + ((c ^ (r & 7)) << 4);
    *(f32x4*)((char*)lA + off) = va;
    *(f32x4*)((char*)lB + off) = vb;
  }
  __syncthreads();

  const int wave = tid >> 6, lane = tid & 63;
  f32x4 acc[4][4];
#pragma unroll
  for (int a = 0; a < 4; ++a)
#pragma unroll
    for (int b = 0; b < 4; ++b) acc[a][b] = (f32x4){0.f, 0.f, 0.f, 0.f};

  mfma_tile(lA, lB, wave, lane, acc);

  // ---- epilogue: transpose-free coalescing via LDS f32 tile ----
  __syncthreads();                       // waves done reading lA/lB
  float* lc = (float*)lds2;              // 128x128 f32 = 64 KB
  const int wr = wave >> 1, wc = wave & 1;
#pragma unroll
  for (int a = 0; a < 4; ++a) {
#pragma unroll
    for (int b = 0; b < 4; ++b) {
      const int col = wc * 64 + b * 16 + (lane & 15);
#pragma unroll
      for (int j = 0; j < 4; ++j) {
        const int row = wr * 64 + a * 16 + (lane >> 4) * 4 + j;
        // XOR col bit4 with row bit2 -> 2-way bank aliasing (free)
        lc[row * 128 + (col ^ (((row >> 2) & 1) << 4))] = acc[a][b][j];
      }
    }
  }
  __syncthreads();

  const float* snb = sn + bh * SEQ + tn * 128;
  const size_t outbase = (size_t)bh * SEQ * SEQ + (size_t)tm * 128 * SEQ + tn * 128;
  const int c = tid & 31;                // f32x4 chunk within row (fixed per thread)
  const int r0 = tid >> 5;               // rows r0, r0+8, ..., r0+120
  const f32x4 s4 = *(const f32x4*)(snb + c * 4);
#pragma unroll
  for (int p = 0; p < 16; ++p) {
    const int row = r0 + p * 8;
    const int cs = c ^ (((row >> 2) & 1) << 2);     // same bit, chunk units
    f32x4 v = *(const f32x4*)&lc[row * 128 + cs * 4];
    v = v * s4;
    __builtin_nontemporal_store(v, (f32x4*)(out + outbase + (size_t)row * SEQ + c * 4));
  }
}

// ---------- launch ----------
extern "C" void kernel_launch(void* const* d_in, const int* in_sizes, int n_in,
                              void* d_out, int out_size, void* d_ws, size_t ws_size,
                              hipStream_t stream) {
  const float* q = (const float*)d_in[0];
  const float* k = (const float*)d_in[1];
  const float* S = (const float*)d_in[2];
  float* out = (float*)d_out;
  char* ws = (char*)d_ws;

  // workspace layout (bytes)
  const size_t off_Sq  = 0;                     // 65536*128*2 = 16 MiB
  const size_t off_Sg  = 16777216;              // 16 MiB
  const size_t off_sn  = 33554432;              // 256 KiB
  const size_t off_cnt = 33849344;              // 256 B
  const size_t off_wl  = 33849600;              // worklist

  u16*   Sqb = (u16*)(ws + off_Sq);
  u16*   Sgn = (u16*)(ws + off_Sg);
  float* sn  = (float*)(ws + off_sn);
  u32*   cnt = (u32*)(ws + off_cnt);
  u32*   wl  = (u32*)(ws + off_wl);

  u32 wlcap = 0;
  if (ws_size > off_wl + 16) {
    size_t rem = (ws_size - off_wl) / 4;
    wlcap = (u32)(rem > 2097152 ? 2097152 : rem);
  }

  hipMemsetAsync(cnt, 0, 4, stream);
  k_proj<<<1024, 256, 0, stream>>>(q, k, S, Sqb, Sgn, sn, wl, cnt, wlcap);
  k_fix<<<1024, 256, 0, stream>>>(k, S, wl, cnt, Sgn, wlcap);
  dim3 g(16, 16, NBH);
  k_gemm<<<g, 256, 0, stream>>>(Sqb, Sgn, sn, out);
}

// Round 4
// 158.041 us; speedup vs baseline: 8.4048x; 1.0880x over previous
//
#include <hip/hip_runtime.h>
#include <hip/hip_bf16.h>
#include <math.h>

// Problem: B=2,H=16,SQ=SK=2048,D=M=128
#define NBH   32
#define SEQ   2048
#define DD    128
#define MM    128

typedef unsigned short u16;
typedef unsigned int   u32;
typedef float  f32x4  __attribute__((ext_vector_type(4)));
typedef __bf16 bf16x8 __attribute__((ext_vector_type(8)));

#define SCALE_F 0.009791516697777346f  // sqrt(pi/2)/128
#define TAU 0.18f
#define LCAP 4096                      // per-block candidate cap (expected ~210)

// ---------- helpers ----------
static __device__ __forceinline__ u16 f2bf(float f) {
  union { float f; u32 u; } v; v.f = f;
  u32 u = v.u;
  u += 0x7fffu + ((u >> 16) & 1u);   // RNE
  return (u16)(u >> 16);
}

// MFMA on a 128x128 (rows) x 128x128 (cols) pair of bf16 LDS tiles.
// LDS layout: [row][chunk16B], chunk stored at (c ^ (row&7)).
// Wave w: wr=w>>1, wc=w&1 owns 64x64 output; acc[4][4] of f32x4.
static __device__ __forceinline__ void mfma_tile(const u16* lA, const u16* lB,
                                                 int wave, int lane,
                                                 f32x4 acc[4][4]) {
  const int wr = wave >> 1, wc = wave & 1;
  const int lrow = lane & 15, lkg = lane >> 4;
#pragma unroll
  for (int kk = 0; kk < 4; ++kk) {
    bf16x8 af[4], bfr[4];
    const int c = kk * 4 + lkg;
#pragma unroll
    for (int a = 0; a < 4; ++a) {
      const int r  = wr * 64 + a * 16 + lrow;
      const int r2 = wc * 64 + a * 16 + lrow;
      af[a]  = *(const bf16x8*)((const char*)lA + r  * 256 + ((c ^ (r  & 7)) << 4));
      bfr[a] = *(const bf16x8*)((const char*)lB + r2 * 256 + ((c ^ (r2 & 7)) << 4));
    }
#pragma unroll
    for (int a = 0; a < 4; ++a)
#pragma unroll
      for (int b = 0; b < 4; ++b)
        acc[a][b] = __builtin_amdgcn_mfma_f32_16x16x32_bf16(af[a], bfr[b], acc[a][b], 0, 0, 0);
  }
}

// stage a 128x128 f32 matrix (row-major, ld=128) into swizzled bf16 LDS
static __device__ __forceinline__ void stage_f32_to_bf16(const float* __restrict__ src,
                                                         u16* lds, int tid) {
#pragma unroll
  for (int j = 0; j < 8; ++j) {
    int i = tid + j * 256;             // bf16 16B-chunk index
    int r = i >> 4, c = i & 15;
    const f32x4* gp = (const f32x4*)(src + (size_t)r * DD + c * 8);
    f32x4 v0 = gp[0], v1 = gp[1];
    union { u16 h[8]; f32x4 v; } pk;
    pk.h[0] = f2bf(v0.x); pk.h[1] = f2bf(v0.y); pk.h[2] = f2bf(v0.z); pk.h[3] = f2bf(v0.w);
    pk.h[4] = f2bf(v1.x); pk.h[5] = f2bf(v1.y); pk.h[6] = f2bf(v1.z); pk.h[7] = f2bf(v1.w);
    *(f32x4*)((char*)lds + r * 256 + ((c ^ (r & 7)) << 4)) = pk.v;
  }
}

// ---------- kernel P: projection rows(128-tile) @ S^T via MFMA ----------
// Also: converts S f32->bf16 per block, and (for K blocks) computes
// sn[row] = SCALE * ||k_row|| from the L2-hot rows.
__global__ __launch_bounds__(256) void k_proj(
    const float* __restrict__ Q, const float* __restrict__ K,
    const float* __restrict__ S, u16* __restrict__ Sqb, u16* __restrict__ Sgn,
    float* __restrict__ sn,
    u32* __restrict__ wl, u32* __restrict__ wlcnt, u32 wlcap) {
  __shared__ __align__(16) u16 lA[128 * 128];   // reused as candidate buffer post-MFMA
  __shared__ __align__(16) u16 lB[128 * 128];
  __shared__ u32 lcnt, lbase;
  const int tid = threadIdx.x;
  const int tile = blockIdx.x;           // 0..511 q, 512..1023 k
  const bool isK = (tile >= 512);
  const int row0 = (isK ? (tile - 512) : tile) * 128;
  const float* src = isK ? K : Q;

  if (tid == 0) lcnt = 0;

  // stage S (f32 -> bf16 swizzled) and A rows
  stage_f32_to_bf16(S, lB, tid);
  stage_f32_to_bf16(src + (size_t)row0 * DD, lA, tid);

  // norms for K rows (rows are L1/L2-hot from staging): 2 threads per row
  if (isK) {
    const int row = tid >> 1, half = tid & 1;
    const f32x4* base = (const f32x4*)(src + (size_t)(row0 + row) * DD) + half * 16;
    float s = 0.f;
#pragma unroll
    for (int j = 0; j < 16; ++j) {
      f32x4 v = base[j];
      s += v.x * v.x + v.y * v.y + v.z * v.z + v.w * v.w;
    }
    s += __shfl_xor(s, 1);
    if (half == 0) sn[row0 + row] = SCALE_F * sqrtf(s);
  }
  __syncthreads();

  const int wave = tid >> 6, lane = tid & 63;
  f32x4 acc[4][4];
#pragma unroll
  for (int a = 0; a < 4; ++a)
#pragma unroll
    for (int b = 0; b < 4; ++b) acc[a][b] = (f32x4){0.f, 0.f, 0.f, 0.f};

  mfma_tile(lA, lB, wave, lane, acc);

  // all waves done reading lA before it is reused as the candidate buffer
  __syncthreads();
  u32* lbuf = (u32*)lA;

  const int wr = wave >> 1, wc = wave & 1;
#pragma unroll
  for (int a = 0; a < 4; ++a) {
#pragma unroll
    for (int b = 0; b < 4; ++b) {
      const int rloc = wr * 64 + a * 16 + (lane >> 4) * 4;
      const int m = wc * 64 + b * 16 + (lane & 15);
#pragma unroll
      for (int j = 0; j < 4; ++j) {
        const float v = acc[a][b][j];
        const int row = row0 + rloc + j;
        if (!isK) {
          Sqb[(size_t)row * MM + m] = f2bf(v);
        } else {
          Sgn[(size_t)row * MM + m] = (v >= 0.f) ? 0x3F80 : 0xBF80;
          if (fabsf(v) < TAU && wlcap) {
            u32 p = atomicAdd(&lcnt, 1u);          // LDS atomic (cheap)
            u32 code = ((u32)row << 7) | (u32)m;
            if (p < LCAP) lbuf[p] = code;
            else {                                  // ~never: direct fallback
              u32 idx = atomicAdd(wlcnt, 1u);
              if (idx < wlcap) wl[idx] = code;
            }
          }
        }
      }
    }
  }

  if (isK && wlcap) {
    __syncthreads();
    if (tid == 0) {
      u32 n = lcnt; if (n > LCAP) n = LCAP;
      lbase = n ? atomicAdd(wlcnt, n) : 0u;         // ONE global atomic per block
    }
    __syncthreads();
    u32 n = lcnt; if (n > LCAP) n = LCAP;
    for (u32 i = tid; i < n; i += 256) {
      u32 dst = lbase + i;
      if (dst < wlcap) wl[dst] = lbuf[i];
    }
  }
}

// ---------- kernel R: f64 recompute of borderline signs ----------
__global__ __launch_bounds__(256) void k_fix(
    const float* __restrict__ K, const float* __restrict__ S,
    const u32* __restrict__ wl, const u32* __restrict__ wlcnt,
    u16* __restrict__ Sgn, u32 wlcap) {
  u32 n = *wlcnt; if (n > wlcap) n = wlcap;
  u32 g = blockIdx.x * 256 + threadIdx.x;
  for (u32 e = g; e < n; e += 256u * 1024u) {
    u32 code = wl[e];
    u32 row = code >> 7, m = code & 127u;
    const f32x4* kr = (const f32x4*)(K + (size_t)row * DD);
    const f32x4* sr = (const f32x4*)(S + (size_t)m * DD);
    double acc = 0.0;
#pragma unroll 8
    for (int d = 0; d < 32; ++d) {
      f32x4 a = kr[d], b = sr[d];
      acc += (double)a.x * b.x + (double)a.y * b.y
           + (double)a.z * b.z + (double)a.w * b.w;
    }
    Sgn[(size_t)row * MM + m] = (acc >= 0.0) ? 0x3F80 : 0xBF80;
  }
}

// ---------- kernel G: out = (Sq @ sign^T) * sn[col], per head ----------
// Staging: global_load_lds dwordx4 with pre-swizzled global source (linear LDS
// dest; read-side applies the same c^(r&7) involution). XCD-chunked block
// swizzle keeps each XCD's reads on 4 bh (= 4 MB = its L2).
__global__ __launch_bounds__(256) void k_gemm(
    const u16* __restrict__ Sqb, const u16* __restrict__ Sgn,
    const float* __restrict__ sn, float* __restrict__ out) {
  __shared__ __align__(16) u16 lds2[2 * 128 * 128];   // 64 KB
  u16* lA = lds2;
  u16* lB = lds2 + 128 * 128;
  const int tid = threadIdx.x;
  const u32 id = blockIdx.x;                 // 0..8191
  const u32 l = (id & 7) * 1024 + (id >> 3); // bijective XCD-chunk swizzle
  const int tn = l & 15, tm = (l >> 4) & 15, bh = l >> 8;
  const u16* Abase = Sqb + ((size_t)bh * SEQ + tm * 128) * MM;
  const u16* Bbase = Sgn + ((size_t)bh * SEQ + tn * 128) * MM;

  {
    typedef __attribute__((address_space(3))) char lds_t;
    typedef const __attribute__((address_space(1))) char glob_t;
    const int wv = tid >> 6, ln = tid & 63;
#pragma unroll
    for (int j = 0; j < 8; ++j) {
      const int s = j * 256 + wv * 64 + ln;                 // dest chunk slot (linear)
      const int r = s >> 4, cp = s & 15;
      const int srcoff = r * 256 + ((cp ^ (r & 7)) << 4);   // pre-swizzled source (bytes)
      __builtin_amdgcn_global_load_lds((glob_t*)((const char*)Abase + srcoff),
                                       (lds_t*)((char*)lA + s * 16), 16, 0, 0);
      __builtin_amdgcn_global_load_lds((glob_t*)((const char*)Bbase + srcoff),
                                       (lds_t*)((char*)lB + s * 16), 16, 0, 0);
    }
  }
  __syncthreads();

  const int wave = tid >> 6, lane = tid & 63;
  f32x4 acc[4][4];
#pragma unroll
  for (int a = 0; a < 4; ++a)
#pragma unroll
    for (int b = 0; b < 4; ++b) acc[a][b] = (f32x4){0.f, 0.f, 0.f, 0.f};

  mfma_tile(lA, lB, wave, lane, acc);

  // ---- epilogue: transpose-free coalescing via LDS f32 tile ----
  __syncthreads();                       // waves done reading lA/lB
  float* lc = (float*)lds2;              // 128x128 f32 = 64 KB
  const int wr = wave >> 1, wc = wave & 1;
#pragma unroll
  for (int a = 0; a < 4; ++a) {
#pragma unroll
    for (int b = 0; b < 4; ++b) {
      const int col = wc * 64 + b * 16 + (lane & 15);
#pragma unroll
      for (int j = 0; j < 4; ++j) {
        const int row = wr * 64 + a * 16 + (lane >> 4) * 4 + j;
        // XOR col bit4 with row bit2 -> 2-way bank aliasing (free)
        lc[row * 128 + (col ^ (((row >> 2) & 1) << 4))] = acc[a][b][j];
      }
    }
  }
  __syncthreads();

  const float* snb = sn + bh * SEQ + tn * 128;
  const size_t outbase = (size_t)bh * SEQ * SEQ + (size_t)tm * 128 * SEQ + tn * 128;
  const int c = tid & 31;                // f32x4 chunk within row (fixed per thread)
  const int r0 = tid >> 5;               // rows r0, r0+8, ..., r0+120
  const f32x4 s4 = *(const f32x4*)(snb + c * 4);
#pragma unroll
  for (int p = 0; p < 16; ++p) {
    const int row = r0 + p * 8;
    const int cs = c ^ (((row >> 2) & 1) << 2);     // same bit, chunk units
    f32x4 v = *(const f32x4*)&lc[row * 128 + cs * 4];
    v = v * s4;
    __builtin_nontemporal_store(v, (f32x4*)(out + outbase + (size_t)row * SEQ + c * 4));
  }
}

// ---------- launch ----------
extern "C" void kernel_launch(void* const* d_in, const int* in_sizes, int n_in,
                              void* d_out, int out_size, void* d_ws, size_t ws_size,
                              hipStream_t stream) {
  const float* q = (const float*)d_in[0];
  const float* k = (const float*)d_in[1];
  const float* S = (const float*)d_in[2];
  float* out = (float*)d_out;
  char* ws = (char*)d_ws;

  // workspace layout (bytes)
  const size_t off_Sq  = 0;                     // 65536*128*2 = 16 MiB
  const size_t off_Sg  = 16777216;              // 16 MiB
  const size_t off_sn  = 33554432;              // 256 KiB
  const size_t off_cnt = 33849344;              // 256 B
  const size_t off_wl  = 33849600;              // worklist

  u16*   Sqb = (u16*)(ws + off_Sq);
  u16*   Sgn = (u16*)(ws + off_Sg);
  float* sn  = (float*)(ws + off_sn);
  u32*   cnt = (u32*)(ws + off_cnt);
  u32*   wl  = (u32*)(ws + off_wl);

  u32 wlcap = 0;
  if (ws_size > off_wl + 16) {
    size_t rem = (ws_size - off_wl) / 4;
    wlcap = (u32)(rem > 2097152 ? 2097152 : rem);
  }

  hipMemsetAsync(cnt, 0, 4, stream);
  k_proj<<<1024, 256, 0, stream>>>(q, k, S, Sqb, Sgn, sn, wl, cnt, wlcap);
  k_fix<<<1024, 256, 0, stream>>>(k, S, wl, cnt, Sgn, wlcap);
  k_gemm<<<8192, 256, 0, stream>>>(Sqb, Sgn, sn, out);
}

// Round 5
// 157.729 us; speedup vs baseline: 8.4214x; 1.0020x over previous
//
#include <hip/hip_runtime.h>
#include <hip/hip_bf16.h>
#include <math.h>

// Problem: B=2,H=16,SQ=SK=2048,D=M=128
#define NBH   32
#define SEQ   2048
#define DD    128
#define MM    128

typedef unsigned short u16;
typedef unsigned int   u32;
typedef float  f32x4  __attribute__((ext_vector_type(4)));
typedef __bf16 bf16x8 __attribute__((ext_vector_type(8)));

#define SCALE_F 0.009791516697777346f  // sqrt(pi/2)/128
#define TAU 0.18f
#define CCAP 2048                      // per-block candidate cap (expected ~205)

// ---------- helpers ----------
static __device__ __forceinline__ u16 f2bf(float f) {
  union { float f; u32 u; } v; v.f = f;
  u32 u = v.u;
  u += 0x7fffu + ((u >> 16) & 1u);   // RNE
  return (u16)(u >> 16);
}

// exact-sign f64 dot of K row (global) with S row m
static __device__ __forceinline__ u16 f64_sign(const float* __restrict__ K,
                                               const float* __restrict__ S,
                                               int row_g, int m) {
  const f32x4* kr = (const f32x4*)(K + (size_t)row_g * DD);
  const f32x4* sr = (const f32x4*)(S + (size_t)m * DD);
  double a0 = 0, a1 = 0, a2 = 0, a3 = 0;
#pragma unroll
  for (int d = 0; d < 32; d += 4) {
    f32x4 x0 = kr[d],   y0 = sr[d];
    f32x4 x1 = kr[d+1], y1 = sr[d+1];
    f32x4 x2 = kr[d+2], y2 = sr[d+2];
    f32x4 x3 = kr[d+3], y3 = sr[d+3];
    a0 += (double)x0.x*y0.x + (double)x0.y*y0.y + (double)x0.z*y0.z + (double)x0.w*y0.w;
    a1 += (double)x1.x*y1.x + (double)x1.y*y1.y + (double)x1.z*y1.z + (double)x1.w*y1.w;
    a2 += (double)x2.x*y2.x + (double)x2.y*y2.y + (double)x2.z*y2.z + (double)x2.w*y2.w;
    a3 += (double)x3.x*y3.x + (double)x3.y*y3.y + (double)x3.z*y3.z + (double)x3.w*y3.w;
  }
  return (((a0 + a1) + (a2 + a3)) >= 0.0) ? 0x3F80 : 0xBF80;
}

// MFMA on a 128x128 (rows) x 128x128 (cols) pair of bf16 LDS tiles.
// LDS layout: [row][chunk16B], chunk stored at (c ^ (row&7)).
static __device__ __forceinline__ void mfma_tile(const u16* lA, const u16* lB,
                                                 int wave, int lane,
                                                 f32x4 acc[4][4]) {
  const int wr = wave >> 1, wc = wave & 1;
  const int lrow = lane & 15, lkg = lane >> 4;
#pragma unroll
  for (int kk = 0; kk < 4; ++kk) {
    bf16x8 af[4], bfr[4];
    const int c = kk * 4 + lkg;
#pragma unroll
    for (int a = 0; a < 4; ++a) {
      const int r  = wr * 64 + a * 16 + lrow;
      const int r2 = wc * 64 + a * 16 + lrow;
      af[a]  = *(const bf16x8*)((const char*)lA + r  * 256 + ((c ^ (r  & 7)) << 4));
      bfr[a] = *(const bf16x8*)((const char*)lB + r2 * 256 + ((c ^ (r2 & 7)) << 4));
    }
#pragma unroll
    for (int a = 0; a < 4; ++a)
#pragma unroll
      for (int b = 0; b < 4; ++b)
        acc[a][b] = __builtin_amdgcn_mfma_f32_16x16x32_bf16(af[a], bfr[b], acc[a][b], 0, 0, 0);
  }
}

// stage a 128x128 f32 matrix (row-major, ld=128) into swizzled bf16 LDS
static __device__ __forceinline__ void stage_f32_to_bf16(const float* __restrict__ src,
                                                         u16* lds, int tid) {
#pragma unroll
  for (int j = 0; j < 8; ++j) {
    int i = tid + j * 256;             // bf16 16B-chunk index
    int r = i >> 4, c = i & 15;
    const f32x4* gp = (const f32x4*)(src + (size_t)r * DD + c * 8);
    f32x4 v0 = gp[0], v1 = gp[1];
    union { u16 h[8]; f32x4 v; } pk;
    pk.h[0] = f2bf(v0.x); pk.h[1] = f2bf(v0.y); pk.h[2] = f2bf(v0.z); pk.h[3] = f2bf(v0.w);
    pk.h[4] = f2bf(v1.x); pk.h[5] = f2bf(v1.y); pk.h[6] = f2bf(v1.z); pk.h[7] = f2bf(v1.w);
    *(f32x4*)((char*)lds + r * 256 + ((c ^ (r & 7)) << 4)) = pk.v;
  }
}

// ---------- kernel P: projection + quantization + in-block f64 fix ----------
__global__ __launch_bounds__(256) void k_proj(
    const float* __restrict__ Q, const float* __restrict__ K,
    const float* __restrict__ S, u16* __restrict__ Sqb, u16* __restrict__ Sgn,
    float* __restrict__ sn) {
  __shared__ __align__(16) u16 lds2[2 * 128 * 128];  // 64 KB, reused as f32 C-tile
  __shared__ u16 cbuf[CCAP];                          // 4 KB candidate list
  __shared__ u32 lcnt;
  u16* lA = lds2;
  u16* lB = lds2 + 128 * 128;
  const int tid = threadIdx.x;
  const int tile = blockIdx.x;           // 0..511 q, 512..1023 k
  const bool isK = (tile >= 512);
  const int row0 = (isK ? (tile - 512) : tile) * 128;
  const float* src = isK ? K : Q;

  if (tid == 0) lcnt = 0;

  // stage S (f32 -> bf16 swizzled) and A rows
  stage_f32_to_bf16(S, lB, tid);
  stage_f32_to_bf16(src + (size_t)row0 * DD, lA, tid);

  // norms for K rows (rows are L1-hot from staging): 2 threads per row
  if (isK) {
    const int row = tid >> 1, half = tid & 1;
    const f32x4* base = (const f32x4*)(src + (size_t)(row0 + row) * DD) + half * 16;
    float s = 0.f;
#pragma unroll
    for (int j = 0; j < 16; ++j) {
      f32x4 v = base[j];
      s += v.x * v.x + v.y * v.y + v.z * v.z + v.w * v.w;
    }
    s += __shfl_xor(s, 1);
    if (half == 0) sn[row0 + row] = SCALE_F * sqrtf(s);
  }
  __syncthreads();

  const int wave = tid >> 6, lane = tid & 63;
  f32x4 acc[4][4];
#pragma unroll
  for (int a = 0; a < 4; ++a)
#pragma unroll
    for (int b = 0; b < 4; ++b) acc[a][b] = (f32x4){0.f, 0.f, 0.f, 0.f};

  mfma_tile(lA, lB, wave, lane, acc);

  // ---- epilogue: acc -> swizzled f32 LDS tile ----
  __syncthreads();                       // waves done reading lA/lB
  float* lc = (float*)lds2;              // 128x128 f32 = 64 KB
  const int wr = wave >> 1, wc = wave & 1;
#pragma unroll
  for (int a = 0; a < 4; ++a) {
#pragma unroll
    for (int b = 0; b < 4; ++b) {
      const int col = wc * 64 + b * 16 + (lane & 15);
#pragma unroll
      for (int j = 0; j < 4; ++j) {
        const int row = wr * 64 + a * 16 + (lane >> 4) * 4 + j;
        lc[row * 128 + (col ^ (((row >> 2) & 1) << 4))] = acc[a][b][j];
      }
    }
  }
  __syncthreads();

  // readback: thread owns 8 consecutive cols (c8) of rows rr, rr+16, ...
  const int c8 = tid & 15;
  const int rr = tid >> 4;
#pragma unroll
  for (int p = 0; p < 8; ++p) {
    const int row = rr + p * 16;
    const int s = (row >> 2) & 1;
    const int cb = (c8 ^ (s << 1)) * 8;          // swizzled element base
    f32x4 v0 = *(const f32x4*)&lc[row * 128 + cb];
    f32x4 v1 = *(const f32x4*)&lc[row * 128 + cb + 4];
    float vals[8] = {v0.x, v0.y, v0.z, v0.w, v1.x, v1.y, v1.z, v1.w};
    union { u16 h[8]; f32x4 v; } pk;
    const int row_g = row0 + row;
    if (!isK) {
#pragma unroll
      for (int e = 0; e < 8; ++e) pk.h[e] = f2bf(vals[e]);
      *(f32x4*)(Sqb + (size_t)row_g * MM + c8 * 8) = pk.v;
    } else {
#pragma unroll
      for (int e = 0; e < 8; ++e) {
        const int m = c8 * 8 + e;
        u16 sg = (vals[e] >= 0.f) ? 0x3F80 : 0xBF80;
        if (fabsf(vals[e]) < TAU) {
          u32 pos = atomicAdd(&lcnt, 1u);
          if (pos < CCAP) cbuf[pos] = (u16)((row << 7) | m);
          else sg = f64_sign(K, S, row_g, m);    // overflow (~never): patch pre-store
        }
        pk.h[e] = sg;
      }
      *(f32x4*)(Sgn + (size_t)row_g * MM + c8 * 8) = pk.v;
    }
  }

  // ---- in-block f64 fix of borderline signs (K rows L1/L2-hot) ----
  if (isK) {
    __syncthreads();                     // lcnt/cbuf complete; packed stores drained
    u32 n = lcnt; if (n > CCAP) n = CCAP;
    for (u32 i = tid; i < n; i += 256) {
      u32 code = cbuf[i];
      int r = code >> 7, m = code & 127;
      Sgn[(size_t)(row0 + r) * MM + m] = f64_sign(K, S, row0 + r, m);
    }
  }
}

// ---------- kernel G: out = (Sq @ sign^T) * sn[col], per head ----------
// Staging: global_load_lds dwordx4 with pre-swizzled global source (linear LDS
// dest; read-side applies the same c^(r&7) involution). XCD-chunked block
// swizzle keeps each XCD's reads on 4 bh (= 4 MB = its L2).
__global__ __launch_bounds__(256) void k_gemm(
    const u16* __restrict__ Sqb, const u16* __restrict__ Sgn,
    const float* __restrict__ sn, float* __restrict__ out) {
  __shared__ __align__(16) u16 lds2[2 * 128 * 128];   // 64 KB
  u16* lA = lds2;
  u16* lB = lds2 + 128 * 128;
  const int tid = threadIdx.x;
  const u32 id = blockIdx.x;                 // 0..8191
  const u32 l = (id & 7) * 1024 + (id >> 3); // bijective XCD-chunk swizzle
  const int tn = l & 15, tm = (l >> 4) & 15, bh = l >> 8;
  const u16* Abase = Sqb + ((size_t)bh * SEQ + tm * 128) * MM;
  const u16* Bbase = Sgn + ((size_t)bh * SEQ + tn * 128) * MM;

  {
    typedef __attribute__((address_space(3))) char lds_t;
    typedef const __attribute__((address_space(1))) char glob_t;
    const int wv = tid >> 6, ln = tid & 63;
#pragma unroll
    for (int j = 0; j < 8; ++j) {
      const int s = j * 256 + wv * 64 + ln;                 // dest chunk slot (linear)
      const int r = s >> 4, cp = s & 15;
      const int srcoff = r * 256 + ((cp ^ (r & 7)) << 4);   // pre-swizzled source (bytes)
      __builtin_amdgcn_global_load_lds((glob_t*)((const char*)Abase + srcoff),
                                       (lds_t*)((char*)lA + s * 16), 16, 0, 0);
      __builtin_amdgcn_global_load_lds((glob_t*)((const char*)Bbase + srcoff),
                                       (lds_t*)((char*)lB + s * 16), 16, 0, 0);
    }
  }
  __syncthreads();

  const int wave = tid >> 6, lane = tid & 63;
  f32x4 acc[4][4];
#pragma unroll
  for (int a = 0; a < 4; ++a)
#pragma unroll
    for (int b = 0; b < 4; ++b) acc[a][b] = (f32x4){0.f, 0.f, 0.f, 0.f};

  mfma_tile(lA, lB, wave, lane, acc);

  // ---- epilogue: transpose-free coalescing via LDS f32 tile ----
  __syncthreads();                       // waves done reading lA/lB
  float* lc = (float*)lds2;              // 128x128 f32 = 64 KB
  const int wr = wave >> 1, wc = wave & 1;
#pragma unroll
  for (int a = 0; a < 4; ++a) {
#pragma unroll
    for (int b = 0; b < 4; ++b) {
      const int col = wc * 64 + b * 16 + (lane & 15);
#pragma unroll
      for (int j = 0; j < 4; ++j) {
        const int row = wr * 64 + a * 16 + (lane >> 4) * 4 + j;
        lc[row * 128 + (col ^ (((row >> 2) & 1) << 4))] = acc[a][b][j];
      }
    }
  }
  __syncthreads();

  const float* snb = sn + bh * SEQ + tn * 128;
  const size_t outbase = (size_t)bh * SEQ * SEQ + (size_t)tm * 128 * SEQ + tn * 128;
  const int c = tid & 31;                // f32x4 chunk within row (fixed per thread)
  const int r0 = tid >> 5;               // rows r0, r0+8, ..., r0+120
  const f32x4 s4 = *(const f32x4*)(snb + c * 4);
#pragma unroll
  for (int p = 0; p < 16; ++p) {
    const int row = r0 + p * 8;
    const int cs = c ^ (((row >> 2) & 1) << 2);     // same bit, chunk units
    f32x4 v = *(const f32x4*)&lc[row * 128 + cs * 4];
    v = v * s4;
    __builtin_nontemporal_store(v, (f32x4*)(out + outbase + (size_t)row * SEQ + c * 4));
  }
}

// ---------- launch ----------
extern "C" void kernel_launch(void* const* d_in, const int* in_sizes, int n_in,
                              void* d_out, int out_size, void* d_ws, size_t ws_size,
                              hipStream_t stream) {
  const float* q = (const float*)d_in[0];
  const float* k = (const float*)d_in[1];
  const float* S = (const float*)d_in[2];
  float* out = (float*)d_out;
  char* ws = (char*)d_ws;

  // workspace layout (bytes)
  const size_t off_Sq  = 0;                     // 65536*128*2 = 16 MiB
  const size_t off_Sg  = 16777216;              // 16 MiB
  const size_t off_sn  = 33554432;              // 256 KiB

  u16*   Sqb = (u16*)(ws + off_Sq);
  u16*   Sgn = (u16*)(ws + off_Sg);
  float* sn  = (float*)(ws + off_sn);

  k_proj<<<1024, 256, 0, stream>>>(q, k, S, Sqb, Sgn, sn);
  k_gemm<<<8192, 256, 0, stream>>>(Sqb, Sgn, sn, out);
}